// Round 8
// baseline (430.763 us; speedup 1.0000x reference)
//
#include <hip/hip_runtime.h>
#include <hip/hip_bf16.h>

#define EMB 1024
#define SEQ 2048
#define BATCH 2
#define HEADS 16
#define HDIM 64
#define ROWS (BATCH*SEQ)   // 4096

typedef __hip_bfloat16 bf16;
typedef __bf16 bf16x8 __attribute__((ext_vector_type(8)));
typedef float f32x4 __attribute__((ext_vector_type(4)));

#define AS1 __attribute__((address_space(1)))
#define AS3 __attribute__((address_space(3)))

__device__ __forceinline__ void load_lds16(const void* g, void* l) {
    __builtin_amdgcn_global_load_lds((const AS1 void*)g, (AS3 void*)l, 16, 0, 0);
}

// wait for all but N oldest VMEM ops; then LDS-drain + barrier WITHOUT vmcnt(0)
#define WAITV(N) asm volatile("s_waitcnt vmcnt(" #N ")" ::: "memory")
#define BAR_LGKM() asm volatile("s_waitcnt lgkmcnt(0)\n\ts_barrier" ::: "memory")

// gelu_tanh(x) == x * sigmoid(2c(x + 0.044715 x^3)), c = sqrt(2/pi)
__device__ __forceinline__ float gelu_f(float x) {
    float y = 1.5957691216057308f * (x + 0.044715f * x * x * x);
    return x / (1.0f + __expf(-y));
}

// ---------------- transpose+cast: in[R][C] (f32) -> out[C][R] (bf16) ----------------
__global__ void transpose_cast_kernel(const float* __restrict__ in, bf16* __restrict__ out,
                                      int R, int C) {
    __shared__ bf16 tile[32][33];
    int tx = threadIdx.x, ty = threadIdx.y;
    int c0 = blockIdx.x * 32, r0 = blockIdx.y * 32;
    for (int i = ty; i < 32; i += 8)
        tile[i][tx] = (bf16)in[(size_t)(r0 + i) * C + c0 + tx];
    __syncthreads();
    for (int i = ty; i < 32; i += 8)
        out[(size_t)(c0 + i) * R + r0 + tx] = tile[tx][i];
}

// batched 1024x1024 transpose+cast for the 4 square weights (one launch)
__global__ void transpose_cast4_kernel(const float* __restrict__ w0, const float* __restrict__ w1,
                                       const float* __restrict__ w2, const float* __restrict__ w3,
                                       bf16* __restrict__ o0, bf16* __restrict__ o1,
                                       bf16* __restrict__ o2, bf16* __restrict__ o3) {
    __shared__ bf16 tile[32][33];
    int z = blockIdx.z;
    const float* in = (z == 0) ? w0 : (z == 1) ? w1 : (z == 2) ? w2 : w3;
    bf16* out = (z == 0) ? o0 : (z == 1) ? o1 : (z == 2) ? o2 : o3;
    int tx = threadIdx.x, ty = threadIdx.y;
    int c0 = blockIdx.x * 32, r0 = blockIdx.y * 32;
    for (int i = ty; i < 32; i += 8)
        tile[i][tx] = (bf16)in[(size_t)(r0 + i) * 1024 + c0 + tx];
    __syncthreads();
    for (int i = ty; i < 32; i += 8)
        out[(size_t)(c0 + i) * 1024 + r0 + tx] = tile[tx][i];
}

// ---------------- per-head V transpose: v[b][s][h*64+d] -> vt[(b*16+h)][d][s] (bf16) ----------------
__global__ void transpose_v_kernel(const bf16* __restrict__ v, bf16* __restrict__ vt) {
    __shared__ bf16 tile[32][33];
    int tx = threadIdx.x, ty = threadIdx.y;
    int bh = blockIdx.z;
    const bf16* in = v + (size_t)(bh >> 4) * SEQ * EMB + (bh & 15) * HDIM;
    bf16* out = vt + (size_t)bh * HDIM * SEQ;
    int s0 = blockIdx.x * 32, d0 = blockIdx.y * 32;
    for (int i = ty; i < 32; i += 8)
        tile[i][tx] = in[(size_t)(s0 + i) * EMB + d0 + tx];
    __syncthreads();
    for (int i = ty; i < 32; i += 8)
        out[(size_t)(d0 + i) * SEQ + s0 + tx] = tile[tx][i];
}

// ---------------- layernorm (ddof=1): f32 in, bf16 out, f32 stats ----------------
__global__ __launch_bounds__(256) void layernorm_kernel(const float* __restrict__ x,
                                                        bf16* __restrict__ out,
                                                        const float* __restrict__ scale,
                                                        const float* __restrict__ shift) {
    int row = blockIdx.x;
    int t = threadIdx.x;
    const float* xr = x + (size_t)row * EMB;
    float v[4];
    float s = 0.f, s2 = 0.f;
#pragma unroll
    for (int i = 0; i < 4; i++) {
        v[i] = xr[t + 256 * i];
        s += v[i];
        s2 += v[i] * v[i];
    }
#pragma unroll
    for (int off = 32; off > 0; off >>= 1) {
        s += __shfl_down(s, off);
        s2 += __shfl_down(s2, off);
    }
    __shared__ float sh[8];
    __shared__ float stats[2];
    int lane = t & 63, wid = t >> 6;
    if (lane == 0) { sh[wid] = s; sh[wid + 4] = s2; }
    __syncthreads();
    if (t == 0) {
        float ts = sh[0] + sh[1] + sh[2] + sh[3];
        float ts2 = sh[4] + sh[5] + sh[6] + sh[7];
        float mean = ts / (float)EMB;
        float var = (ts2 - (float)EMB * mean * mean) / (float)(EMB - 1);
        stats[0] = mean;
        stats[1] = rsqrtf(var + 1e-5f);
    }
    __syncthreads();
    float mean = stats[0], inv = stats[1];
#pragma unroll
    for (int i = 0; i < 4; i++) {
        int c = t + 256 * i;
        float y = (v[i] - mean) * inv * scale[c] + shift[c];
        out[(size_t)row * EMB + c] = (bf16)y;
    }
}

// XCD-aware swizzle (heuristic): per-XCD fixed set of 4 A-row-panels.
__device__ __forceinline__ void swz32(int id, int& bx, int& by) {
    int xcd = id & 7, m = id >> 3;
    by = xcd + 8 * (m & 3);
    bx = m >> 2;
}
__device__ __forceinline__ void swz64(int id, int& bx, int& by) {
    int xcd = id & 7, m = id >> 3;
    by = xcd + 8 * (m & 3) + 32 * (m >> 6);
    bx = (m >> 2) & 15;
}

// ---------------- 128x128 GEMM, 3-stage pipelined K-loop (BK=32) ----------------
// C[M][N] = A[M][K](bf16) * BT[N][K](bf16)^T + bias(f32); M must be 4096.
// Per step: vmcnt(4) drains only this step's loads; barrier does NOT drain
// in-flight prefetches (raw s_barrier + lgkmcnt only); loads get ~2 steps of latency.
template <int ACT, int RES, int OUTF>
__global__ __launch_bounds__(256) void gemm_kernel(const bf16* __restrict__ A,
                                                   const bf16* __restrict__ BT,
                                                   void* __restrict__ Cout,
                                                   const float* __restrict__ bias,
                                                   const float* __restrict__ res,
                                                   int M, int N, int K) {
    __shared__ __align__(16) bf16 lA[3][128 * 32];
    __shared__ __align__(16) bf16 lB[3][128 * 32];
    int tid = threadIdx.x;
    int wave = tid >> 6, lane = tid & 63;
    int bx, by;
    swz32(blockIdx.x, bx, by);
    int m0 = by * 128, n0 = bx * 128;
    int wm = (wave >> 1) * 64, wn = (wave & 1) * 64;
    f32x4 acc[4][4] = {};

    int srow = wave * 16 + (lane >> 2);
    int skc = (lane & 3) * 8;
    const bf16* Ag = A + (size_t)(m0 + srow) * K + skc;
    const bf16* Bg = BT + (size_t)(n0 + srow) * K + skc;
    size_t woff = (size_t)(wave * 16) * 32;

    const int an = lane & 15;
    const int ak = (lane >> 4) * 8;

    // prologue: steps 0 and 1
#pragma unroll
    for (int p = 0; p < 2; p++) {
        int k0 = p * 32;
        load_lds16(Ag + k0, lA[p] + woff);
        load_lds16(Ag + (size_t)64 * K + k0, lA[p] + woff + 64 * 32);
        load_lds16(Bg + k0, lB[p] + woff);
        load_lds16(Bg + (size_t)64 * K + k0, lB[p] + woff + 64 * 32);
    }

    int nsteps = K >> 5;
    for (int t = 0; t < nsteps; t++) {
        int buf = t % 3;
        if (t + 1 < nsteps) WAITV(4);
        else                WAITV(0);
        BAR_LGKM();
        if (t + 2 < nsteps) {
            int k0 = (t + 2) * 32;
            int wb = (t + 2) % 3;
            load_lds16(Ag + k0, lA[wb] + woff);
            load_lds16(Ag + (size_t)64 * K + k0, lA[wb] + woff + 64 * 32);
            load_lds16(Bg + k0, lB[wb] + woff);
            load_lds16(Bg + (size_t)64 * K + k0, lB[wb] + woff + 64 * 32);
        }
        bf16x8 af[4], bfv[4];
#pragma unroll
        for (int i = 0; i < 4; i++)
            af[i] = *(const bf16x8*)(lA[buf] + (wm + 16 * i + an) * 32 + ak);
#pragma unroll
        for (int j = 0; j < 4; j++)
            bfv[j] = *(const bf16x8*)(lB[buf] + (wn + 16 * j + an) * 32 + ak);
#pragma unroll
        for (int i = 0; i < 4; i++)
#pragma unroll
            for (int j = 0; j < 4; j++)
                acc[i][j] = __builtin_amdgcn_mfma_f32_16x16x32_bf16(af[i], bfv[j], acc[i][j], 0, 0, 0);
    }
#pragma unroll
    for (int j = 0; j < 4; j++) {
        int col = n0 + wn + 16 * j + an;
        float bv = bias[col];
#pragma unroll
        for (int i = 0; i < 4; i++) {
#pragma unroll
            for (int r = 0; r < 4; r++) {
                int row = m0 + wm + 16 * i + (lane >> 4) * 4 + r;
                float vx = acc[i][j][r] + bv;
                if (ACT == 1) vx = gelu_f(vx);
                size_t idx = (size_t)row * N + col;
                if (RES == 2) vx += res[idx];
                if (OUTF == 0) ((bf16*)Cout)[idx] = (bf16)vx;
                else ((float*)Cout)[idx] = vx;
            }
        }
    }
}

// ---------------- 64x64 GEMM, BK=64, 3-stage pipelined (M=4096,N=1024) ----------------
template <int RES, int OUTF>
__global__ __launch_bounds__(256) void gemm64_kernel(const bf16* __restrict__ A,
                                                     const bf16* __restrict__ BT,
                                                     void* __restrict__ Cout,
                                                     const float* __restrict__ bias,
                                                     const float* __restrict__ res,
                                                     int M, int N, int K) {
    __shared__ __align__(16) bf16 lA[3][2][64 * 32];   // [buf][k-half][row][col]
    __shared__ __align__(16) bf16 lB[3][2][64 * 32];
    int tid = threadIdx.x;
    int wave = tid >> 6, lane = tid & 63;
    int bx, by;
    swz64(blockIdx.x, bx, by);
    int m0 = by * 64, n0 = bx * 64;
    int wm = (wave >> 1) * 32, wn = (wave & 1) * 32;
    f32x4 acc[2][2] = {};

    int srow = wave * 16 + (lane >> 2);
    int skc = (lane & 3) * 8;
    const bf16* Ag = A + (size_t)(m0 + srow) * K + skc;
    const bf16* Bg = BT + (size_t)(n0 + srow) * K + skc;
    size_t woff = (size_t)(wave * 16) * 32;

    const int an = lane & 15;
    const int ak = (lane >> 4) * 8;

#pragma unroll
    for (int p = 0; p < 2; p++) {
        int k0 = p * 64;
        load_lds16(Ag + k0, &lA[p][0][woff]);
        load_lds16(Ag + k0 + 32, &lA[p][1][woff]);
        load_lds16(Bg + k0, &lB[p][0][woff]);
        load_lds16(Bg + k0 + 32, &lB[p][1][woff]);
    }

    int nsteps = K >> 6;
    for (int t = 0; t < nsteps; t++) {
        int buf = t % 3;
        if (t + 1 < nsteps) WAITV(4);
        else                WAITV(0);
        BAR_LGKM();
        if (t + 2 < nsteps) {
            int k0 = (t + 2) * 64;
            int wb = (t + 2) % 3;
            load_lds16(Ag + k0, &lA[wb][0][woff]);
            load_lds16(Ag + k0 + 32, &lA[wb][1][woff]);
            load_lds16(Bg + k0, &lB[wb][0][woff]);
            load_lds16(Bg + k0 + 32, &lB[wb][1][woff]);
        }
#pragma unroll
        for (int h = 0; h < 2; h++) {
            bf16x8 af[2], bfv[2];
#pragma unroll
            for (int i = 0; i < 2; i++)
                af[i] = *(const bf16x8*)(&lA[buf][h][(wm + 16 * i + an) * 32 + ak]);
#pragma unroll
            for (int j = 0; j < 2; j++)
                bfv[j] = *(const bf16x8*)(&lB[buf][h][(wn + 16 * j + an) * 32 + ak]);
#pragma unroll
            for (int i = 0; i < 2; i++)
#pragma unroll
                for (int j = 0; j < 2; j++)
                    acc[i][j] = __builtin_amdgcn_mfma_f32_16x16x32_bf16(af[i], bfv[j], acc[i][j], 0, 0, 0);
        }
    }
#pragma unroll
    for (int j = 0; j < 2; j++) {
        int col = n0 + wn + 16 * j + an;
        float bv = bias[col];
#pragma unroll
        for (int i = 0; i < 2; i++) {
#pragma unroll
            for (int r = 0; r < 4; r++) {
                int row = m0 + wm + 16 * i + (lane >> 4) * 4 + r;
                float vx = acc[i][j][r] + bv;
                size_t idx = (size_t)row * N + col;
                if (RES == 2) vx += res[idx];
                if (OUTF == 0) ((bf16*)Cout)[idx] = (bf16)vx;
                else ((float*)Cout)[idx] = vx;
            }
        }
    }
}

// ---------------- fused QKV GEMM (3-stage pipelined): A[4096][1024] x WqkvT[3072][1024]^T ----------------
__global__ __launch_bounds__(256) void gemm_qkv_kernel(const bf16* __restrict__ A,
                                                       const bf16* __restrict__ BT,
                                                       bf16* __restrict__ qo,
                                                       bf16* __restrict__ ko,
                                                       bf16* __restrict__ vo,
                                                       const float* __restrict__ bq,
                                                       const float* __restrict__ bk,
                                                       const float* __restrict__ bv) {
    const int K = EMB;
    __shared__ __align__(16) bf16 lA[3][128 * 32];
    __shared__ __align__(16) bf16 lB[3][128 * 32];
    int tid = threadIdx.x;
    int wave = tid >> 6, lane = tid & 63;
    int bx, by;
    swz32(blockIdx.x, bx, by);
    int m0 = by * 128, n0 = bx * 128;
    int wm = (wave >> 1) * 64, wn = (wave & 1) * 64;
    f32x4 acc[4][4] = {};

    int srow = wave * 16 + (lane >> 2);
    int skc = (lane & 3) * 8;
    const bf16* Ag = A + (size_t)(m0 + srow) * K + skc;
    const bf16* Bg = BT + (size_t)(n0 + srow) * K + skc;
    size_t woff = (size_t)(wave * 16) * 32;

    const int an = lane & 15;
    const int ak = (lane >> 4) * 8;

#pragma unroll
    for (int p = 0; p < 2; p++) {
        int k0 = p * 32;
        load_lds16(Ag + k0, lA[p] + woff);
        load_lds16(Ag + (size_t)64 * K + k0, lA[p] + woff + 64 * 32);
        load_lds16(Bg + k0, lB[p] + woff);
        load_lds16(Bg + (size_t)64 * K + k0, lB[p] + woff + 64 * 32);
    }

    const int nsteps = K >> 5;
    for (int t = 0; t < nsteps; t++) {
        int buf = t % 3;
        if (t + 1 < nsteps) WAITV(4);
        else                WAITV(0);
        BAR_LGKM();
        if (t + 2 < nsteps) {
            int k0 = (t + 2) * 32;
            int wb = (t + 2) % 3;
            load_lds16(Ag + k0, lA[wb] + woff);
            load_lds16(Ag + (size_t)64 * K + k0, lA[wb] + woff + 64 * 32);
            load_lds16(Bg + k0, lB[wb] + woff);
            load_lds16(Bg + (size_t)64 * K + k0, lB[wb] + woff + 64 * 32);
        }
        bf16x8 af[4], bfv[4];
#pragma unroll
        for (int i = 0; i < 4; i++)
            af[i] = *(const bf16x8*)(lA[buf] + (wm + 16 * i + an) * 32 + ak);
#pragma unroll
        for (int j = 0; j < 4; j++)
            bfv[j] = *(const bf16x8*)(lB[buf] + (wn + 16 * j + an) * 32 + ak);
#pragma unroll
        for (int i = 0; i < 4; i++)
#pragma unroll
            for (int j = 0; j < 4; j++)
                acc[i][j] = __builtin_amdgcn_mfma_f32_16x16x32_bf16(af[i], bfv[j], acc[i][j], 0, 0, 0);
    }
#pragma unroll
    for (int j = 0; j < 4; j++) {
        int col = n0 + wn + 16 * j + an;
        int region = col >> 10;
        int c = col & 1023;
        const float* bias = (region == 0) ? bq : (region == 1) ? bk : bv;
        bf16* outp = (region == 0) ? qo : (region == 1) ? ko : vo;
        float scl = (region == 0) ? 0.125f : 1.0f;
        float bvv = bias[c];
#pragma unroll
        for (int i = 0; i < 4; i++) {
#pragma unroll
            for (int r = 0; r < 4; r++) {
                int row = m0 + wm + 16 * i + (lane >> 4) * 4 + r;
                float vx = (acc[i][j][r] + bvv) * scl;
                outp[(size_t)row * EMB + c] = (bf16)vx;
            }
        }
    }
}

// ---------------- causal flash attention, no-max softmax, 3-stage LDS pipeline ----------------
__global__ __launch_bounds__(256) void attn_kernel(const bf16* __restrict__ q,
                                                   const bf16* __restrict__ k,
                                                   const bf16* __restrict__ vt,
                                                   bf16* __restrict__ ctx) {
    __shared__ __align__(16) bf16 ksm[3][2048];
    __shared__ __align__(16) bf16 vsm[3][2048];
    __shared__ __align__(16) bf16 pbuf[4][16][32];
    int tid = threadIdx.x;
    int wave = tid >> 6, lane = tid & 63;
    int id = blockIdx.x;
    int bh = id >> 5;
    int bx = ((id & 31) + bh) & 31;
    int b = bh >> 4, h = bh & 15;
    int q0 = bx * 64 + wave * 16;
    const bf16* qp = q + (size_t)b * SEQ * EMB + h * HDIM;
    const bf16* kp = k + (size_t)b * SEQ * EMB + h * HDIM;
    const bf16* vp = vt + (size_t)bh * HDIM * SEQ;

    int an = lane & 15;
    int aq = lane >> 4;
    bf16x8 qf0 = *(const bf16x8*)(qp + (size_t)(q0 + an) * EMB + aq * 8);
    bf16x8 qf1 = *(const bf16x8*)(qp + (size_t)(q0 + an) * EMB + 32 + aq * 8);
    f32x4 o[4] = {};
    float lp[4] = {0.f, 0.f, 0.f, 0.f};

    const bf16* kg = kp + (size_t)((wave & 1) * 16 + (lane >> 2)) * EMB + ((wave & 2) ? 32 : 0) + (lane & 3) * 8;
    const bf16* vg = vp + (size_t)(wave * 16 + (lane >> 2)) * SEQ + (lane & 3) * 8;

    int nsteps = 2 * bx + 2;
    // prologue: steps 0 and 1 (nsteps >= 2 always)
    load_lds16(kg, (char*)ksm[0] + wave * 1024);
    load_lds16(vg, (char*)vsm[0] + wave * 1024);
    load_lds16(kg + (size_t)32 * EMB, (char*)ksm[1] + wave * 1024);
    load_lds16(vg + 32, (char*)vsm[1] + wave * 1024);

    for (int t = 0; t < nsteps; t++) {
        int buf = t % 3;
        if (t + 1 < nsteps) WAITV(2);
        else                WAITV(0);
        BAR_LGKM();
        if (t + 2 < nsteps) {
            int kvn = (t + 2) * 32;
            int wb = (t + 2) % 3;
            load_lds16(kg + (size_t)kvn * EMB, (char*)ksm[wb] + wave * 1024);
            load_lds16(vg + kvn, (char*)vsm[wb] + wave * 1024);
        }
        const char* kb = (const char*)ksm[buf];
        bf16x8 kf0 = *(const bf16x8*)(kb + an * 64 + aq * 16);
        bf16x8 kf1 = *(const bf16x8*)(kb + 2048 + an * 64 + aq * 16);
        bf16x8 kf2 = *(const bf16x8*)(kb + (16 + an) * 64 + aq * 16);
        bf16x8 kf3 = *(const bf16x8*)(kb + 2048 + (16 + an) * 64 + aq * 16);
        f32x4 s0 = {}, s1 = {};
        s0 = __builtin_amdgcn_mfma_f32_16x16x32_bf16(qf0, kf0, s0, 0, 0, 0);
        s0 = __builtin_amdgcn_mfma_f32_16x16x32_bf16(qf1, kf1, s0, 0, 0, 0);
        s1 = __builtin_amdgcn_mfma_f32_16x16x32_bf16(qf0, kf2, s1, 0, 0, 0);
        s1 = __builtin_amdgcn_mfma_f32_16x16x32_bf16(qf1, kf3, s1, 0, 0, 0);
        int kv = t * 32;
        if (t < nsteps - 2) {
#pragma unroll
            for (int r = 0; r < 4; r++) {
                float p0 = __expf(s0[r]);
                float p1 = __expf(s1[r]);
                lp[r] += p0 + p1;
                pbuf[wave][aq * 4 + r][an] = (bf16)p0;
                pbuf[wave][aq * 4 + r][16 + an] = (bf16)p1;
            }
        } else {
#pragma unroll
            for (int r = 0; r < 4; r++) {
                int row = q0 + aq * 4 + r;
                float p0 = (kv + an > row) ? 0.f : __expf(s0[r]);
                float p1 = (kv + 16 + an > row) ? 0.f : __expf(s1[r]);
                lp[r] += p0 + p1;
                pbuf[wave][aq * 4 + r][an] = (bf16)p0;
                pbuf[wave][aq * 4 + r][16 + an] = (bf16)p1;
            }
        }
        asm volatile("s_waitcnt lgkmcnt(0)" ::: "memory");
        bf16x8 pa = *(const bf16x8*)(&pbuf[wave][an][aq * 8]);
        const char* vb = (const char*)vsm[buf];
#pragma unroll
        for (int dt = 0; dt < 4; dt++) {
            bf16x8 vf = *(const bf16x8*)(vb + (dt * 16 + an) * 64 + aq * 16);
            o[dt] = __builtin_amdgcn_mfma_f32_16x16x32_bf16(pa, vf, o[dt], 0, 0, 0);
        }
    }
#pragma unroll
    for (int r = 0; r < 4; r++) {
        float v = lp[r];
        v += __shfl_xor(v, 1);
        v += __shfl_xor(v, 2);
        v += __shfl_xor(v, 4);
        v += __shfl_xor(v, 8);
        lp[r] = v;
    }
#pragma unroll
    for (int dt = 0; dt < 4; dt++) {
#pragma unroll
        for (int r = 0; r < 4; r++) {
            int row = q0 + aq * 4 + r;
            int col = h * HDIM + dt * 16 + an;
            ctx[((size_t)b * SEQ + row) * EMB + col] = (bf16)(o[dt][r] / lp[r]);
        }
    }
}

extern "C" void kernel_launch(void* const* d_in, const int* in_sizes, int n_in,
                              void* d_out, int out_size, void* d_ws, size_t ws_size,
                              hipStream_t stream) {
    const float* x = (const float*)d_in[0];
    const float* Wq = (const float*)d_in[1];
    const float* bq = (const float*)d_in[2];
    const float* Wk = (const float*)d_in[3];
    const float* bk = (const float*)d_in[4];
    const float* Wv = (const float*)d_in[5];
    const float* bv = (const float*)d_in[6];
    const float* Wo = (const float*)d_in[7];
    const float* bo = (const float*)d_in[8];
    const float* W1 = (const float*)d_in[9];
    const float* b1 = (const float*)d_in[10];
    const float* W2 = (const float*)d_in[11];
    const float* b2 = (const float*)d_in[12];
    const float* ln1s = (const float*)d_in[13];
    const float* ln1b = (const float*)d_in[14];
    const float* ln2s = (const float*)d_in[15];
    const float* ln2b = (const float*)d_in[16];
    float* out = (float*)d_out;

    char* ws = (char*)d_ws;
    const size_t MB = 1ull << 20;
    bf16* WqT = (bf16*)(ws + 0 * MB);    // WqT/WkT/WvT contiguous = [3072][1024]
    bf16* WkT = (bf16*)(ws + 2 * MB);
    bf16* WvT = (bf16*)(ws + 4 * MB);
    bf16* WoT = (bf16*)(ws + 6 * MB);
    bf16* W1T = (bf16*)(ws + 8 * MB);    // [4096][1024]
    bf16* W2T = (bf16*)(ws + 16 * MB);   // [1024][4096]
    bf16* hbuf = (bf16*)(ws + 24 * MB);
    bf16* qbuf = (bf16*)(ws + 32 * MB);
    bf16* kbuf = (bf16*)(ws + 40 * MB);
    bf16* vbuf = (bf16*)(ws + 48 * MB);
    bf16* vtb = (bf16*)(ws + 56 * MB);
    bf16* ctxb = (bf16*)(ws + 64 * MB);
    float* x1 = (float*)(ws + 72 * MB);  // fp32 residual, 16MB
    bf16* hff = (bf16*)(ws + 32 * MB);   // overlaps q/k/v/vt (dead by FFN)

    dim3 tb(32, 8);
    transpose_cast4_kernel<<<dim3(32, 32, 4), tb, 0, stream>>>(Wq, Wk, Wv, Wo, WqT, WkT, WvT, WoT);
    transpose_cast_kernel<<<dim3(128, 32), tb, 0, stream>>>(W1, W1T, 1024, 4096);
    transpose_cast_kernel<<<dim3(32, 128), tb, 0, stream>>>(W2, W2T, 4096, 1024);

    layernorm_kernel<<<ROWS, 256, 0, stream>>>(x, hbuf, ln1s, ln1b);

    // fused QKV: N=3072, 768 blocks, swizzled
    gemm_qkv_kernel<<<768, 256, 0, stream>>>(hbuf, WqT, qbuf, kbuf, vbuf, bq, bk, bv);

    transpose_v_kernel<<<dim3(64, 2, 32), tb, 0, stream>>>(vbuf, vtb);

    attn_kernel<<<1024, 256, 0, stream>>>(qbuf, kbuf, vtb, ctxb);

    // x1 = x + ctx @ Wo + bo   (f32 out, f32 residual)
    gemm64_kernel<2, 1><<<1024, 256, 0, stream>>>(ctxb, WoT, x1, bo, x, ROWS, EMB, EMB);

    layernorm_kernel<<<ROWS, 256, 0, stream>>>(x1, hbuf, ln2s, ln2b);

    // hff = gelu(h2 @ W1 + b1)
    gemm_kernel<1, 0, 0><<<1024, 256, 0, stream>>>(hbuf, W1T, hff, b1, nullptr, ROWS, 4 * EMB, EMB);

    // out = x1 + hff @ W2 + b2   (f32 out, f32 residual)
    gemm64_kernel<2, 1><<<1024, 256, 0, stream>>>(hff, W2T, out, b2, x1, ROWS, EMB, 4 * EMB);
}